// Round 2
// baseline (3216.019 us; speedup 1.0000x reference)
//
#include <hip/hip_runtime.h>
#include <hip/hip_bf16.h>
#include <cstdint>
#include <cstddef>

#define NATOM 20000
#define NEDGE 320000
#define DD 128
#define HD 441
#define NSLOT 256
#define BN_EPS 1e-5f

// ---------------------------------------------------------------------------
// ws layout (floats):
//   Vloc   [NATOM*96]        = 1,920,000
//   W3m    [128*128]         folded W3 @ W_m[128:,:]
//   bfold  [128]             b3 @ W_m[128:,:] + b_m
//   a1,bb1,a2,bb2 [128] each (BN affine folded: bn(x) = x*a + bb)
//   slots  [4 * NSLOT*128]   partial sums/sumsq for BN1, BN2
// Y (layer activations) lives in d_out and is overwritten in place per layer.
// ---------------------------------------------------------------------------

__global__ __launch_bounds__(256) void k_vlocal(const float* __restrict__ hV,
                                                const float* __restrict__ Wva,
                                                const float* __restrict__ bva,
                                                float* __restrict__ Vloc) {
    int o = blockIdx.x * blockDim.x + threadIdx.x;
    const int total = NATOM * 96;
    const int stride = gridDim.x * blockDim.x;
    for (; o < total; o += stride) {
        int r = o / 96, c = o % 96;
        const float* hv = hV + (size_t)r * DD;
        float acc = bva[c];
#pragma unroll 8
        for (int k = 0; k < DD; ++k) acc += hv[k] * Wva[k * 96 + c];
        Vloc[o] = acc;
    }
}

__global__ __launch_bounds__(256) void k_w3m(const float* __restrict__ W3,
                                             const float* __restrict__ b3,
                                             const float* __restrict__ Wm,
                                             const float* __restrict__ bm,
                                             float* __restrict__ W3m,
                                             float* __restrict__ bfold) {
    int o = blockIdx.x * blockDim.x + threadIdx.x;
    if (o < 16384) {
        int k = o >> 7, c = o & 127;
        float acc = 0.f;
#pragma unroll 8
        for (int j = 0; j < 128; ++j) acc += W3[k * 128 + j] * Wm[(128 + j) * 128 + c];
        W3m[o] = acc;
    } else if (o < 16512) {
        int c = o - 16384;
        float acc = bm[c];
        for (int j = 0; j < 128; ++j) acc += b3[j] * Wm[(128 + j) * 128 + c];
        bfold[c] = acc;
    }
}

// Fused: per-edge geometric features (H, 441 cols, built in LDS) + L1 GEMM.
__global__ __launch_bounds__(256) void k_feat_l1(
        const float* __restrict__ hE, const float* __restrict__ rot,
        const float* __restrict__ trans, const float* __restrict__ rbf,
        const long long* __restrict__ eidx, const float* __restrict__ Vloc,
        const float* __restrict__ Wvd, const float* __restrict__ bvd,
        const float* __restrict__ W1, const float* __restrict__ b1,
        float* __restrict__ Y, float* __restrict__ gsum, float* __restrict__ gsq) {
    __shared__ float Hs[16][444];      // H tile (441 used, padded)
    __shared__ float hEs[16][128];
    __shared__ float Vds[16][96];
    __shared__ float trs[16][3];
    __shared__ int srcI[16], dstI[16];
    __shared__ float bsum[128], bsq[128];

    const int t = threadIdx.x;
    const int e0 = blockIdx.x * 16;

    // int64/int32 sniff for edge_idx (reference says int64; harness doc is
    // ambiguous). For a true little-endian int64 buffer with values <2^31 the
    // odd 32-bit words are all zero; for a random int32 index buffer the
    // probability of three zeros is ~1e-13.
    const int* e32 = (const int*)eidx;
    const bool is64 = (e32[1] == 0) && (e32[3] == 0) && (e32[5] == 0);

    if (t < 16) {
        int s, d;
        if (is64) { s = (int)eidx[e0 + t]; d = (int)eidx[NEDGE + e0 + t]; }
        else      { s = e32[e0 + t];       d = e32[NEDGE + e0 + t]; }
        s = min(max(s, 0), NATOM - 1);
        d = min(max(d, 0), NATOM - 1);
        srcI[t] = s; dstI[t] = d;
    }
    if (t >= 128) { bsum[t - 128] = 0.f; bsq[t - 128] = 0.f; }
    for (int o = t; o < 16 * 128; o += 256) {
        int e = o >> 7, k = o & 127;
        hEs[e][k] = hE[(size_t)(e0 + e) * DD + k];
    }
    // quat (9), rbf (16), trans (3): 28 scalars per edge
    for (int o = t; o < 16 * 28; o += 256) {
        int e = o / 28, q = o % 28;
        if (q < 9)       Hs[e][384 + q]      = rot[(size_t)(e0 + e) * 9 + q];
        else if (q < 25) Hs[e][393 + q - 9]  = rbf[(size_t)(e0 + e) * 16 + q - 9];
        else             trs[e][q - 25]      = trans[(size_t)(e0 + e) * 3 + q - 25];
    }
    __syncthreads();

    // V_edge (H[0:96]) = hE @ Wvd + bvd ; Vs gather (H[96:192]) ; Vd gather
    for (int o = t; o < 16 * 96; o += 256) {
        int e = o / 96, c = o % 96;
        float acc = bvd[c];
#pragma unroll 8
        for (int k = 0; k < DD; ++k) acc += hEs[e][k] * Wvd[k * 96 + c];
        Hs[e][c]      = acc;
        Hs[e][96 + c] = Vloc[(size_t)srcI[e] * 96 + c];
        Vds[e][c]     = Vloc[(size_t)dstI[e] * 96 + c];
    }
    __syncthreads();

    // Qt (H[192:384]): Qt[n][i] = sum_j R[i][j]*Ks[n][j] + trans[i]
    for (int o = t; o < 16 * 192; o += 256) {
        int e = o / 192, rem = o % 192, n = rem / 3, i = rem % 3;
        float acc = trs[e][i];
#pragma unroll
        for (int j = 0; j < 3; ++j) acc += Hs[e][384 + i * 3 + j] * Hs[e][n * 3 + j];
        Hs[e][192 + n * 3 + i] = acc;
    }
    // QRK (H[409:441]): sum_i Vd[a][i] * (R @ Vs[a])[i]
    for (int o = t; o < 16 * 32; o += 256) {
        int e = o >> 5, a = o & 31;
        float q = 0.f;
#pragma unroll
        for (int i = 0; i < 3; ++i) {
            float rk = 0.f;
#pragma unroll
            for (int j = 0; j < 3; ++j) rk += Hs[e][384 + i * 3 + j] * Hs[e][96 + a * 3 + j];
            q += Vds[e][a * 3 + i] * rk;
        }
        Hs[e][409 + a] = q;
    }
    __syncthreads();

    // GEMM: Y1[16][128] = Hs[16][441] @ W1[441][128] + b1
    const int cq = t & 31;     // column quad: cols 4*cq .. 4*cq+3
    const int eh = t >> 5;     // 0..7 -> edges eh, eh+8
    const int c0 = cq * 4;
    float acc0[4], acc1[4];
#pragma unroll
    for (int q = 0; q < 4; ++q) { acc0[q] = b1[c0 + q]; acc1[q] = acc0[q]; }
#pragma unroll 4
    for (int k = 0; k < HD; ++k) {
        const float4 w = *reinterpret_cast<const float4*>(&W1[(size_t)k * 128 + c0]);
        const float a0 = Hs[eh][k];
        const float a1 = Hs[eh + 8][k];
        acc0[0] += a0 * w.x; acc0[1] += a0 * w.y; acc0[2] += a0 * w.z; acc0[3] += a0 * w.w;
        acc1[0] += a1 * w.x; acc1[1] += a1 * w.y; acc1[2] += a1 * w.z; acc1[3] += a1 * w.w;
    }
    *reinterpret_cast<float4*>(&Y[(size_t)(e0 + eh) * 128 + c0]) =
        make_float4(acc0[0], acc0[1], acc0[2], acc0[3]);
    *reinterpret_cast<float4*>(&Y[(size_t)(e0 + eh + 8) * 128 + c0]) =
        make_float4(acc1[0], acc1[1], acc1[2], acc1[3]);
#pragma unroll
    for (int q = 0; q < 4; ++q) {
        atomicAdd(&bsum[c0 + q], acc0[q] + acc1[q]);
        atomicAdd(&bsq[c0 + q], acc0[q] * acc0[q] + acc1[q] * acc1[q]);
    }
    __syncthreads();
    if (t < 128) {
        const int slot = blockIdx.x & (NSLOT - 1);
        atomicAdd(&gsum[slot * 128 + t], bsum[t]);
        atomicAdd(&gsq[slot * 128 + t], bsq[t]);
    }
}

__global__ __launch_bounds__(128) void k_stats(const float* __restrict__ gsum,
                                               const float* __restrict__ gsq,
                                               const float* __restrict__ g,
                                               const float* __restrict__ be,
                                               float* __restrict__ a,
                                               float* __restrict__ bb) {
    const int c = threadIdx.x;
    float S = 0.f, Q = 0.f;
    for (int s = 0; s < NSLOT; ++s) { S += gsum[s * 128 + c]; Q += gsq[s * 128 + c]; }
    const float mean = S / (float)NEDGE;
    const float var  = Q / (float)NEDGE - mean * mean;
    const float av   = g[c] * rsqrtf(var + BN_EPS);
    a[c]  = av;
    bb[c] = be[c] - mean * av;
}

// Y2 = relu(bn1(Y1)) @ W2 + b2, in place on Y; accumulate BN2 stats.
__global__ __launch_bounds__(256) void k_l2(float* __restrict__ Y,
                                            const float* __restrict__ a1,
                                            const float* __restrict__ bb1,
                                            const float* __restrict__ W2,
                                            const float* __restrict__ b2,
                                            float* __restrict__ gsum,
                                            float* __restrict__ gsq) {
    __shared__ float Xs[16][132];
    __shared__ float bsum[128], bsq[128];
    const int t = threadIdx.x;
    const int e0 = blockIdx.x * 16;
    if (t < 128) { bsum[t] = 0.f; bsq[t] = 0.f; }
    for (int o = t; o < 16 * 128; o += 256) {
        int e = o >> 7, k = o & 127;
        float x = Y[(size_t)(e0 + e) * 128 + k] * a1[k] + bb1[k];
        Xs[e][k] = fmaxf(x, 0.f);
    }
    __syncthreads();
    const int cq = t & 31, eh = t >> 5, c0 = cq * 4;
    float acc0[4], acc1[4];
#pragma unroll
    for (int q = 0; q < 4; ++q) { acc0[q] = b2[c0 + q]; acc1[q] = acc0[q]; }
#pragma unroll 4
    for (int k = 0; k < 128; ++k) {
        const float4 w = *reinterpret_cast<const float4*>(&W2[(size_t)k * 128 + c0]);
        const float x0 = Xs[eh][k];
        const float x1 = Xs[eh + 8][k];
        acc0[0] += x0 * w.x; acc0[1] += x0 * w.y; acc0[2] += x0 * w.z; acc0[3] += x0 * w.w;
        acc1[0] += x1 * w.x; acc1[1] += x1 * w.y; acc1[2] += x1 * w.z; acc1[3] += x1 * w.w;
    }
    *reinterpret_cast<float4*>(&Y[(size_t)(e0 + eh) * 128 + c0]) =
        make_float4(acc0[0], acc0[1], acc0[2], acc0[3]);
    *reinterpret_cast<float4*>(&Y[(size_t)(e0 + eh + 8) * 128 + c0]) =
        make_float4(acc1[0], acc1[1], acc1[2], acc1[3]);
#pragma unroll
    for (int q = 0; q < 4; ++q) {
        atomicAdd(&bsum[c0 + q], acc0[q] + acc1[q]);
        atomicAdd(&bsq[c0 + q], acc0[q] * acc0[q] + acc1[q] * acc1[q]);
    }
    __syncthreads();
    if (t < 128) {
        const int slot = blockIdx.x & (NSLOT - 1);
        atomicAdd(&gsum[slot * 128 + t], bsum[t]);
        atomicAdd(&gsq[slot * 128 + t], bsq[t]);
    }
}

// out = relu(bn2(Y2)) @ W3m + h_E @ Wm_top + bfold, in place on Y (=d_out).
__global__ __launch_bounds__(256) void k_l3(float* __restrict__ Y,
                                            const float* __restrict__ hE,
                                            const float* __restrict__ a2,
                                            const float* __restrict__ bb2,
                                            const float* __restrict__ W3m,
                                            const float* __restrict__ Wm,
                                            const float* __restrict__ bfold) {
    __shared__ float Xs[16][132];
    __shared__ float hEs[16][132];
    const int t = threadIdx.x;
    const int e0 = blockIdx.x * 16;
    for (int o = t; o < 16 * 128; o += 256) {
        int e = o >> 7, k = o & 127;
        float x = Y[(size_t)(e0 + e) * 128 + k] * a2[k] + bb2[k];
        Xs[e][k]  = fmaxf(x, 0.f);
        hEs[e][k] = hE[(size_t)(e0 + e) * 128 + k];
    }
    __syncthreads();
    const int cq = t & 31, eh = t >> 5, c0 = cq * 4;
    float acc0[4], acc1[4];
#pragma unroll
    for (int q = 0; q < 4; ++q) { acc0[q] = bfold[c0 + q]; acc1[q] = acc0[q]; }
#pragma unroll 4
    for (int k = 0; k < 128; ++k) {
        const float4 w3 = *reinterpret_cast<const float4*>(&W3m[(size_t)k * 128 + c0]);
        const float4 wm = *reinterpret_cast<const float4*>(&Wm[(size_t)k * 128 + c0]);
        const float x0 = Xs[eh][k],  x1 = Xs[eh + 8][k];
        const float h0 = hEs[eh][k], h1 = hEs[eh + 8][k];
        acc0[0] += x0 * w3.x + h0 * wm.x; acc0[1] += x0 * w3.y + h0 * wm.y;
        acc0[2] += x0 * w3.z + h0 * wm.z; acc0[3] += x0 * w3.w + h0 * wm.w;
        acc1[0] += x1 * w3.x + h1 * wm.x; acc1[1] += x1 * w3.y + h1 * wm.y;
        acc1[2] += x1 * w3.z + h1 * wm.z; acc1[3] += x1 * w3.w + h1 * wm.w;
    }
    *reinterpret_cast<float4*>(&Y[(size_t)(e0 + eh) * 128 + c0]) =
        make_float4(acc0[0], acc0[1], acc0[2], acc0[3]);
    *reinterpret_cast<float4*>(&Y[(size_t)(e0 + eh + 8) * 128 + c0]) =
        make_float4(acc1[0], acc1[1], acc1[2], acc1[3]);
}

extern "C" void kernel_launch(void* const* d_in, const int* in_sizes, int n_in,
                              void* d_out, int out_size, void* d_ws, size_t ws_size,
                              hipStream_t stream) {
    const float* hV    = (const float*)d_in[0];
    const float* hE    = (const float*)d_in[1];
    const float* rot   = (const float*)d_in[2];
    const float* trans = (const float*)d_in[3];
    const float* rbf   = (const float*)d_in[4];
    // d_in[5] = h_E_0 (unused by the reference)
    const float* Wva   = (const float*)d_in[6];
    const float* bva   = (const float*)d_in[7];
    const float* Wvd   = (const float*)d_in[8];
    const float* bvd   = (const float*)d_in[9];
    const float* W1    = (const float*)d_in[10];
    const float* b1    = (const float*)d_in[11];
    const float* g1    = (const float*)d_in[12];
    const float* be1   = (const float*)d_in[13];
    const float* W2    = (const float*)d_in[14];
    const float* b2    = (const float*)d_in[15];
    const float* g2    = (const float*)d_in[16];
    const float* be2   = (const float*)d_in[17];
    const float* W3    = (const float*)d_in[18];
    const float* b3    = (const float*)d_in[19];
    const float* Wm    = (const float*)d_in[20];
    const float* bm    = (const float*)d_in[21];
    const long long* eidx = (const long long*)d_in[22];

    float* ws    = (float*)d_ws;
    float* Vloc  = ws;
    float* W3m   = ws + 1920000;
    float* bfold = W3m + 16384;
    float* a1    = bfold + 128;
    float* bb1   = a1 + 128;
    float* a2    = bb1 + 128;
    float* bb2   = a2 + 128;
    float* slots = bb2 + 128;
    float* gsum1 = slots;
    float* gsq1  = slots + NSLOT * 128;
    float* gsum2 = slots + 2 * NSLOT * 128;
    float* gsq2  = slots + 3 * NSLOT * 128;
    float* Y     = (float*)d_out;

    hipMemsetAsync(slots, 0, (size_t)4 * NSLOT * 128 * sizeof(float), stream);
    k_vlocal<<<2048, 256, 0, stream>>>(hV, Wva, bva, Vloc);
    k_w3m<<<65, 256, 0, stream>>>(W3, b3, Wm, bm, W3m, bfold);
    k_feat_l1<<<NEDGE / 16, 256, 0, stream>>>(hE, rot, trans, rbf, eidx, Vloc,
                                              Wvd, bvd, W1, b1, Y, gsum1, gsq1);
    k_stats<<<1, 128, 0, stream>>>(gsum1, gsq1, g1, be1, a1, bb1);
    k_l2<<<NEDGE / 16, 256, 0, stream>>>(Y, a1, bb1, W2, b2, gsum2, gsq2);
    k_stats<<<1, 128, 0, stream>>>(gsum2, gsq2, g2, be2, a2, bb2);
    k_l3<<<NEDGE / 16, 256, 0, stream>>>(Y, hE, a2, bb2, W3m, Wm, bfold);
}

// Round 4
// 749.851 us; speedup vs baseline: 4.2889x; 4.2889x over previous
//
#include <hip/hip_runtime.h>
#include <hip/hip_bf16.h>
#include <cstdint>
#include <cstddef>

#define NATOM 20000
#define NEDGE 320000
#define DD 128
#define NSLOT 256
#define BN_EPS 1e-5f

typedef short bf16x8 __attribute__((ext_vector_type(8)));   // 8 bf16 (4 VGPRs)
typedef float f32x4  __attribute__((ext_vector_type(4)));

__device__ inline short f2bf(float f) {
    union { float f; unsigned u; } v; v.f = f;
    unsigned r = v.u + 0x7fffu + ((v.u >> 16) & 1u);   // RNE
    return (short)(r >> 16);
}
__device__ inline float bf2f(short s) {
    union { unsigned u; float f; } v; v.u = ((unsigned)(unsigned short)s) << 16;
    return v.f;
}
__device__ inline bf16x8 cvt8(const float* p) {
    float4 x = *(const float4*)p; float4 y = *(const float4*)(p + 4);
    bf16x8 r;
    r[0]=f2bf(x.x); r[1]=f2bf(x.y); r[2]=f2bf(x.z); r[3]=f2bf(x.w);
    r[4]=f2bf(y.x); r[5]=f2bf(y.y); r[6]=f2bf(y.z); r[7]=f2bf(y.w);
    return r;
}
#define MFMA(a,b,c) __builtin_amdgcn_mfma_f32_16x16x32_bf16((a),(b),(c),0,0,0)

// ---------------------------------------------------------------------------
// ws layout (floats): Vloc[1920000] | W3m[16384] | bfold[128] | a1,bb1,a2,bb2
// | slots[4*NSLOT*128] ; then (as short*): W1p[57344] Wvdp[16384] W2p[16384]
// W3mp[16384] Wmp[16384]  — frag-packed bf16 weights.
// Pack layout: dst[((kk*8+ct)*64+lane)*8+j] = W[kk*32+8*(lane>>4)+j][ct*16+(lane&15)]
// ---------------------------------------------------------------------------

__global__ __launch_bounds__(256) void k_vlocal(const float* __restrict__ hV,
                                                const float* __restrict__ Wva,
                                                const float* __restrict__ bva,
                                                float* __restrict__ Vloc) {
    int o = blockIdx.x * blockDim.x + threadIdx.x;
    const int total = NATOM * 96;
    const int stride = gridDim.x * blockDim.x;
    for (; o < total; o += stride) {
        int r = o / 96, c = o % 96;
        const float* hv = hV + (size_t)r * DD;
        float acc = bva[c];
#pragma unroll 8
        for (int k = 0; k < DD; ++k) acc += hv[k] * Wva[k * 96 + c];
        Vloc[o] = acc;
    }
}

__global__ __launch_bounds__(256) void k_w3m(const float* __restrict__ W3,
                                             const float* __restrict__ b3,
                                             const float* __restrict__ Wm,
                                             const float* __restrict__ bm,
                                             float* __restrict__ W3m,
                                             float* __restrict__ bfold) {
    int o = blockIdx.x * blockDim.x + threadIdx.x;
    if (o < 16384) {
        int k = o >> 7, c = o & 127;
        float acc = 0.f;
#pragma unroll 8
        for (int j = 0; j < 128; ++j) acc += W3[k * 128 + j] * Wm[(128 + j) * 128 + c];
        W3m[o] = acc;
    } else if (o < 16512) {
        int c = o - 16384;
        float acc = bm[c];
        for (int j = 0; j < 128; ++j) acc += b3[j] * Wm[(128 + j) * 128 + c];
        bfold[c] = acc;
    }
}

// Pack fp32 weight [Ksrc][Nsrc] into MFMA-frag-ordered bf16, K padded to Kpad,
// N padded to 128 (zeros). One elem per thread.
__global__ __launch_bounds__(256) void k_pack(const float* __restrict__ src,
                                              short* __restrict__ dst,
                                              int Ksrc, int Nsrc, int Kpad) {
    int total = (Kpad / 32) * 8 * 64 * 8;
    for (int o = blockIdx.x * blockDim.x + threadIdx.x; o < total;
         o += gridDim.x * blockDim.x) {
        int j = o & 7, lane = (o >> 3) & 63, ct = (o >> 9) & 7, kk = o >> 12;
        int k = kk * 32 + (lane >> 4) * 8 + j;
        int c = ct * 16 + (lane & 15);
        float v = (k < Ksrc && c < Nsrc) ? src[(size_t)k * Nsrc + c] : 0.f;
        dst[o] = f2bf(v);
    }
}

// Fused: geometric features (bf16 H tile in LDS) + V_edge MFMA + L1 MFMA.
__global__ __launch_bounds__(256) void k_feat_l1(
        const float* __restrict__ hE, const float* __restrict__ rot,
        const float* __restrict__ trans, const float* __restrict__ rbf,
        const long long* __restrict__ eidx, const float* __restrict__ Vloc,
        const short* __restrict__ Wvdp, const float* __restrict__ bvd,
        const short* __restrict__ W1p, const float* __restrict__ b1,
        float* __restrict__ Y, float* __restrict__ gsum, float* __restrict__ gsq) {
    __shared__ short Hs[32][456];     // bf16 H tile, 441 used + zero pad
    __shared__ short Vds[32][96];     // Vd gather (bf16)
    __shared__ float rotS[32][9];
    __shared__ float trsS[32][3];
    __shared__ int srcI[32], dstI[32];
    __shared__ float bsum[128], bsq[128];

    const int t = threadIdx.x;
    const int e0 = blockIdx.x * 32;
    const int lane = t & 63, w = t >> 6;

    const int* e32a = (const int*)eidx;
    const bool is64 = (e32a[1] == 0) && (e32a[3] == 0) && (e32a[5] == 0);
    if (t < 32) {
        int s, d;
        if (is64) { s = (int)eidx[e0 + t]; d = (int)eidx[NEDGE + e0 + t]; }
        else      { s = e32a[e0 + t];      d = e32a[NEDGE + e0 + t]; }
        srcI[t] = min(max(s, 0), NATOM - 1);
        dstI[t] = min(max(d, 0), NATOM - 1);
    }
    if (t < 128) { bsum[t] = 0.f; bsq[t] = 0.f; }
    __syncthreads();

    // ---- Phase A: stage small features + gathers (cols 96..191, 384..455)
    for (int o = t; o < 32 * 9; o += 256) {
        int e = o / 9, q = o % 9;
        float v = rot[(size_t)(e0 + e) * 9 + q];
        rotS[e][q] = v; Hs[e][384 + q] = f2bf(v);
    }
    for (int o = t; o < 32 * 3; o += 256) {
        int e = o / 3, q = o % 3;
        trsS[e][q] = trans[(size_t)(e0 + e) * 3 + q];
    }
    for (int o = t; o < 32 * 16; o += 256) {
        int e = o >> 4, q = o & 15;
        Hs[e][393 + q] = f2bf(rbf[(size_t)(e0 + e) * 16 + q]);
    }
    for (int o = t; o < 32 * 15; o += 256) {       // zero K-pad cols 441..455
        int e = o / 15, q = o % 15;
        Hs[e][441 + q] = 0;
    }
    for (int o = t; o < 32 * 96; o += 256) {
        int e = o / 96, c = o % 96;
        Hs[e][96 + c] = f2bf(Vloc[(size_t)srcI[e] * 96 + c]);
        Vds[e][c]     = f2bf(Vloc[(size_t)dstI[e] * 96 + c]);
    }

    // ---- Phase B: V_edge = hE @ Wvd (N padded 128; cols >=96 dropped)
    {
        bf16x8 a[2][4];
#pragma unroll
        for (int rt = 0; rt < 2; ++rt) {
            const float* rowp = hE + (size_t)(e0 + rt * 16 + (lane & 15)) * 128;
#pragma unroll
            for (int kk = 0; kk < 4; ++kk)
                a[rt][kk] = cvt8(rowp + kk * 32 + (lane >> 4) * 8);
        }
        f32x4 acc[2][2] = {};
#pragma unroll
        for (int ct2 = 0; ct2 < 2; ++ct2) {
            const int ct = w * 2 + ct2;
#pragma unroll
            for (int kk = 0; kk < 4; ++kk) {
                bf16x8 b = *(const bf16x8*)(Wvdp + ((size_t)(kk * 8 + ct) * 64 + lane) * 8);
                acc[0][ct2] = MFMA(a[0][kk], b, acc[0][ct2]);
                acc[1][ct2] = MFMA(a[1][kk], b, acc[1][ct2]);
            }
        }
#pragma unroll
        for (int ct2 = 0; ct2 < 2; ++ct2) {
            const int c = (w * 2 + ct2) * 16 + (lane & 15);
            if (c < 96) {
                const float bb = bvd[c];
#pragma unroll
                for (int rt = 0; rt < 2; ++rt)
#pragma unroll
                    for (int r = 0; r < 4; ++r) {
                        int e = rt * 16 + (lane >> 4) * 4 + r;
                        Hs[e][c] = f2bf(acc[rt][ct2][r] + bb);
                    }
            }
        }
    }
    __syncthreads();

    // ---- Phase C: Qt (cols 192..383) and QRK (cols 409..440)
    for (int o = t; o < 32 * 192; o += 256) {
        int e = o / 192, rem = o % 192, n = rem / 3, i = rem % 3;
        float acc = trsS[e][i];
#pragma unroll
        for (int j = 0; j < 3; ++j) acc += rotS[e][3 * i + j] * bf2f(Hs[e][n * 3 + j]);
        Hs[e][192 + n * 3 + i] = f2bf(acc);
    }
    for (int o = t; o < 32 * 32; o += 256) {
        int e = o >> 5, aa = o & 31;
        float q = 0.f;
#pragma unroll
        for (int i = 0; i < 3; ++i) {
            float rk = 0.f;
#pragma unroll
            for (int j = 0; j < 3; ++j) rk += rotS[e][3 * i + j] * bf2f(Hs[e][96 + aa * 3 + j]);
            q += bf2f(Vds[e][aa * 3 + i]) * rk;
        }
        Hs[e][409 + aa] = f2bf(q);
    }
    __syncthreads();

    // ---- Phase D: Y1 = H @ W1 + b1 (K=448 padded), stats into bsum/bsq
    {
        f32x4 acc[2][2] = {};
#pragma unroll 2
        for (int kk = 0; kk < 14; ++kk) {
            bf16x8 a0 = *(const bf16x8*)&Hs[(lane & 15)][kk * 32 + (lane >> 4) * 8];
            bf16x8 a1 = *(const bf16x8*)&Hs[16 + (lane & 15)][kk * 32 + (lane >> 4) * 8];
            bf16x8 b0 = *(const bf16x8*)(W1p + ((size_t)(kk * 8 + 2 * w) * 64 + lane) * 8);
            bf16x8 b1v = *(const bf16x8*)(W1p + ((size_t)(kk * 8 + 2 * w + 1) * 64 + lane) * 8);
            acc[0][0] = MFMA(a0, b0, acc[0][0]);
            acc[1][0] = MFMA(a1, b0, acc[1][0]);
            acc[0][1] = MFMA(a0, b1v, acc[0][1]);
            acc[1][1] = MFMA(a1, b1v, acc[1][1]);
        }
#pragma unroll
        for (int ct2 = 0; ct2 < 2; ++ct2) {
            const int c = (2 * w + ct2) * 16 + (lane & 15);
            const float bias = b1[c];
#pragma unroll
            for (int rt = 0; rt < 2; ++rt) {
                float s = 0.f, sq = 0.f;
#pragma unroll
                for (int r = 0; r < 4; ++r) {
                    int e = rt * 16 + (lane >> 4) * 4 + r;
                    float y = acc[rt][ct2][r] + bias;
                    Y[(size_t)(e0 + e) * 128 + c] = y;
                    s += y; sq += y * y;
                }
                atomicAdd(&bsum[c], s);
                atomicAdd(&bsq[c], sq);
            }
        }
    }
    __syncthreads();
    if (t < 128) {
        const int slot = blockIdx.x & (NSLOT - 1);
        atomicAdd(&gsum[slot * 128 + t], bsum[t]);
        atomicAdd(&gsq[slot * 128 + t], bsq[t]);
    }
}

__global__ __launch_bounds__(128) void k_stats(const float* __restrict__ gsum,
                                               const float* __restrict__ gsq,
                                               const float* __restrict__ g,
                                               const float* __restrict__ be,
                                               float* __restrict__ a,
                                               float* __restrict__ bb) {
    const int c = threadIdx.x;
    float S = 0.f, Q = 0.f;
    for (int s = 0; s < NSLOT; ++s) { S += gsum[s * 128 + c]; Q += gsq[s * 128 + c]; }
    const float mean = S / (float)NEDGE;
    const float var  = Q / (float)NEDGE - mean * mean;
    const float av   = g[c] * rsqrtf(var + BN_EPS);
    a[c]  = av;
    bb[c] = be[c] - mean * av;
}

// Y2 = relu(bn1(Y1)) @ W2 + b2 (MFMA), in place; accumulate BN2 stats.
__global__ __launch_bounds__(256) void k_l2(float* __restrict__ Y,
                                            const float* __restrict__ a1,
                                            const float* __restrict__ bb1,
                                            const short* __restrict__ W2p,
                                            const float* __restrict__ b2,
                                            float* __restrict__ gsum,
                                            float* __restrict__ gsq) {
    __shared__ short Xs[32][136];
    __shared__ float bsum[128], bsq[128];
    const int t = threadIdx.x, lane = t & 63, w = t >> 6;
    const int e0 = blockIdx.x * 32;
    if (t < 128) { bsum[t] = 0.f; bsq[t] = 0.f; }
    for (int o = t; o < 32 * 128; o += 256) {
        int e = o >> 7, k = o & 127;
        float x = Y[(size_t)(e0 + e) * 128 + k] * a1[k] + bb1[k];
        Xs[e][k] = f2bf(fmaxf(x, 0.f));
    }
    __syncthreads();
    f32x4 acc[2][2] = {};
#pragma unroll
    for (int kk = 0; kk < 4; ++kk) {
        bf16x8 a0 = *(const bf16x8*)&Xs[(lane & 15)][kk * 32 + (lane >> 4) * 8];
        bf16x8 a1f = *(const bf16x8*)&Xs[16 + (lane & 15)][kk * 32 + (lane >> 4) * 8];
        bf16x8 b0 = *(const bf16x8*)(W2p + ((size_t)(kk * 8 + 2 * w) * 64 + lane) * 8);
        bf16x8 b1v = *(const bf16x8*)(W2p + ((size_t)(kk * 8 + 2 * w + 1) * 64 + lane) * 8);
        acc[0][0] = MFMA(a0, b0, acc[0][0]);
        acc[1][0] = MFMA(a1f, b0, acc[1][0]);
        acc[0][1] = MFMA(a0, b1v, acc[0][1]);
        acc[1][1] = MFMA(a1f, b1v, acc[1][1]);
    }
#pragma unroll
    for (int ct2 = 0; ct2 < 2; ++ct2) {
        const int c = (2 * w + ct2) * 16 + (lane & 15);
        const float bias = b2[c];
#pragma unroll
        for (int rt = 0; rt < 2; ++rt) {
            float s = 0.f, sq = 0.f;
#pragma unroll
            for (int r = 0; r < 4; ++r) {
                int e = rt * 16 + (lane >> 4) * 4 + r;
                float y = acc[rt][ct2][r] + bias;
                Y[(size_t)(e0 + e) * 128 + c] = y;
                s += y; sq += y * y;
            }
            atomicAdd(&bsum[c], s);
            atomicAdd(&bsq[c], sq);
        }
    }
    __syncthreads();
    if (t < 128) {
        const int slot = blockIdx.x & (NSLOT - 1);
        atomicAdd(&gsum[slot * 128 + t], bsum[t]);
        atomicAdd(&gsq[slot * 128 + t], bsq[t]);
    }
}

// out = relu(bn2(Y2)) @ W3m + hE @ WmTop + bfold (two fused MFMA GEMMs).
__global__ __launch_bounds__(256) void k_l3(float* __restrict__ Y,
                                            const float* __restrict__ hE,
                                            const float* __restrict__ a2,
                                            const float* __restrict__ bb2,
                                            const short* __restrict__ W3mp,
                                            const short* __restrict__ Wmp,
                                            const float* __restrict__ bfold) {
    __shared__ short Xs[32][136];
    __shared__ short Hes[32][136];
    const int t = threadIdx.x, lane = t & 63, w = t >> 6;
    const int e0 = blockIdx.x * 32;
    for (int o = t; o < 32 * 128; o += 256) {
        int e = o >> 7, k = o & 127;
        float x = Y[(size_t)(e0 + e) * 128 + k] * a2[k] + bb2[k];
        Xs[e][k]  = f2bf(fmaxf(x, 0.f));
        Hes[e][k] = f2bf(hE[(size_t)(e0 + e) * 128 + k]);
    }
    __syncthreads();
    f32x4 acc[2][2] = {};
#pragma unroll
    for (int kk = 0; kk < 4; ++kk) {
        bf16x8 x0 = *(const bf16x8*)&Xs[(lane & 15)][kk * 32 + (lane >> 4) * 8];
        bf16x8 x1 = *(const bf16x8*)&Xs[16 + (lane & 15)][kk * 32 + (lane >> 4) * 8];
        bf16x8 h0 = *(const bf16x8*)&Hes[(lane & 15)][kk * 32 + (lane >> 4) * 8];
        bf16x8 h1 = *(const bf16x8*)&Hes[16 + (lane & 15)][kk * 32 + (lane >> 4) * 8];
        bf16x8 w30 = *(const bf16x8*)(W3mp + ((size_t)(kk * 8 + 2 * w) * 64 + lane) * 8);
        bf16x8 w31 = *(const bf16x8*)(W3mp + ((size_t)(kk * 8 + 2 * w + 1) * 64 + lane) * 8);
        bf16x8 wm0 = *(const bf16x8*)(Wmp + ((size_t)(kk * 8 + 2 * w) * 64 + lane) * 8);
        bf16x8 wm1 = *(const bf16x8*)(Wmp + ((size_t)(kk * 8 + 2 * w + 1) * 64 + lane) * 8);
        acc[0][0] = MFMA(x0, w30, acc[0][0]);
        acc[1][0] = MFMA(x1, w30, acc[1][0]);
        acc[0][1] = MFMA(x0, w31, acc[0][1]);
        acc[1][1] = MFMA(x1, w31, acc[1][1]);
        acc[0][0] = MFMA(h0, wm0, acc[0][0]);
        acc[1][0] = MFMA(h1, wm0, acc[1][0]);
        acc[0][1] = MFMA(h0, wm1, acc[0][1]);
        acc[1][1] = MFMA(h1, wm1, acc[1][1]);
    }
#pragma unroll
    for (int ct2 = 0; ct2 < 2; ++ct2) {
        const int c = (2 * w + ct2) * 16 + (lane & 15);
        const float bias = bfold[c];
#pragma unroll
        for (int rt = 0; rt < 2; ++rt)
#pragma unroll
            for (int r = 0; r < 4; ++r) {
                int e = rt * 16 + (lane >> 4) * 4 + r;
                Y[(size_t)(e0 + e) * 128 + c] = acc[rt][ct2][r] + bias;
            }
    }
}

extern "C" void kernel_launch(void* const* d_in, const int* in_sizes, int n_in,
                              void* d_out, int out_size, void* d_ws, size_t ws_size,
                              hipStream_t stream) {
    const float* hV    = (const float*)d_in[0];
    const float* hE    = (const float*)d_in[1];
    const float* rot   = (const float*)d_in[2];
    const float* trans = (const float*)d_in[3];
    const float* rbf   = (const float*)d_in[4];
    const float* Wva   = (const float*)d_in[6];
    const float* bva   = (const float*)d_in[7];
    const float* Wvd   = (const float*)d_in[8];
    const float* bvd   = (const float*)d_in[9];
    const float* W1    = (const float*)d_in[10];
    const float* b1    = (const float*)d_in[11];
    const float* g1    = (const float*)d_in[12];
    const float* be1   = (const float*)d_in[13];
    const float* W2    = (const float*)d_in[14];
    const float* b2    = (const float*)d_in[15];
    const float* g2    = (const float*)d_in[16];
    const float* be2   = (const float*)d_in[17];
    const float* W3    = (const float*)d_in[18];
    const float* b3    = (const float*)d_in[19];
    const float* Wm    = (const float*)d_in[20];
    const float* bm    = (const float*)d_in[21];
    const long long* eidx = (const long long*)d_in[22];

    float* ws    = (float*)d_ws;
    float* Vloc  = ws;
    float* W3m   = ws + 1920000;
    float* bfold = W3m + 16384;
    float* a1    = bfold + 128;
    float* bb1   = a1 + 128;
    float* a2    = bb1 + 128;
    float* bb2   = a2 + 128;
    float* slots = bb2 + 128;
    float* gsum1 = slots;
    float* gsq1  = slots + NSLOT * 128;
    float* gsum2 = slots + 2 * NSLOT * 128;
    float* gsq2  = slots + 3 * NSLOT * 128;
    short* W1p   = (short*)(slots + 4 * NSLOT * 128);
    short* Wvdp  = W1p + 57344;
    short* W2p   = Wvdp + 16384;
    short* W3mp  = W2p + 16384;
    short* Wmp   = W3mp + 16384;
    float* Y     = (float*)d_out;

    hipMemsetAsync(slots, 0, (size_t)4 * NSLOT * 128 * sizeof(float), stream);
    k_vlocal<<<2048, 256, 0, stream>>>(hV, Wva, bva, Vloc);
    k_w3m<<<65, 256, 0, stream>>>(W3, b3, Wm, bm, W3m, bfold);
    k_pack<<<224, 256, 0, stream>>>(W1, W1p, 441, 128, 448);
    k_pack<<<64, 256, 0, stream>>>(Wvd, Wvdp, 128, 96, 128);
    k_pack<<<64, 256, 0, stream>>>(W2, W2p, 128, 128, 128);
    k_pack<<<64, 256, 0, stream>>>(W3m, W3mp, 128, 128, 128);
    k_pack<<<64, 256, 0, stream>>>(Wm, Wmp, 128, 128, 128);
    k_feat_l1<<<NEDGE / 32, 256, 0, stream>>>(hE, rot, trans, rbf, eidx, Vloc,
                                              Wvdp, bvd, W1p, b1, Y, gsum1, gsq1);
    k_stats<<<1, 128, 0, stream>>>(gsum1, gsq1, g1, be1, a1, bb1);
    k_l2<<<NEDGE / 32, 256, 0, stream>>>(Y, a1, bb1, W2p, b2, gsum2, gsq2);
    k_stats<<<1, 128, 0, stream>>>(gsum2, gsq2, g2, be2, a2, bb2);
    k_l3<<<NEDGE / 32, 256, 0, stream>>>(Y, hE, a2, bb2, W3mp, Wmp, bfold);
}

// Round 6
// 476.049 us; speedup vs baseline: 6.7556x; 1.5752x over previous
//
#include <hip/hip_runtime.h>
#include <hip/hip_bf16.h>
#include <cstdint>
#include <cstddef>

#define NATOM 20000
#define NEDGE 320000
#define DD 128
#define NSLOT 256
#define BN_EPS 1e-5f
#define HSTR 488   // Hs row stride in shorts: 976B, 16B-aligned, 2-way-free banks

typedef short bf16x8 __attribute__((ext_vector_type(8)));   // 8 bf16 (4 VGPRs)
typedef float f32x4  __attribute__((ext_vector_type(4)));

__device__ inline short f2bf(float f) {
    union { float f; unsigned u; } v; v.f = f;
    unsigned r = v.u + 0x7fffu + ((v.u >> 16) & 1u);   // RNE
    return (short)(r >> 16);
}
__device__ inline float bf2f(short s) {
    union { unsigned u; float f; } v; v.u = ((unsigned)(unsigned short)s) << 16;
    return v.f;
}
__device__ inline bf16x8 cvt8(const float* p) {
    float4 x = *(const float4*)p; float4 y = *(const float4*)(p + 4);
    bf16x8 r;
    r[0]=f2bf(x.x); r[1]=f2bf(x.y); r[2]=f2bf(x.z); r[3]=f2bf(x.w);
    r[4]=f2bf(y.x); r[5]=f2bf(y.y); r[6]=f2bf(y.z); r[7]=f2bf(y.w);
    return r;
}
#define MFMA(a,b,c) __builtin_amdgcn_mfma_f32_16x16x32_bf16((a),(b),(c),0,0,0)

// ---------------------------------------------------------------------------
// ws layout (floats): Vloc[1920000] | W3m[16384] | bfold[128] | a1,bb1,a2,bb2
// | slots[4*NSLOT*128] ; then (as short*): W1p[57344] Wvdp[16384] W2p[16384]
// W3mp[16384] Wmp[16384] Wvap[16384] — frag-packed bf16 weights.
// Pack layout: dst[((kk*8+ct)*64+lane)*8+j] = W[kk*32+8*(lane>>4)+j][ct*16+(lane&15)]
// ---------------------------------------------------------------------------

// Pack fp32 weight [Ksrc][Nsrc] into MFMA-frag-ordered bf16, K padded to Kpad,
// N padded to 128 (zeros).
__global__ __launch_bounds__(256) void k_pack(const float* __restrict__ src,
                                              short* __restrict__ dst,
                                              int Ksrc, int Nsrc, int Kpad) {
    int total = (Kpad / 32) * 8 * 64 * 8;
    for (int o = blockIdx.x * blockDim.x + threadIdx.x; o < total;
         o += gridDim.x * blockDim.x) {
        int j = o & 7, lane = (o >> 3) & 63, ct = (o >> 9) & 7, kk = o >> 12;
        int k = kk * 32 + (lane >> 4) * 8 + j;
        int c = ct * 16 + (lane & 15);
        float v = (k < Ksrc && c < Nsrc) ? src[(size_t)k * Nsrc + c] : 0.f;
        dst[o] = f2bf(v);
    }
}

// Vloc = hV @ Wva + bva  (MFMA, 32 rows/block)
__global__ __launch_bounds__(256) void k_vlocal(const float* __restrict__ hV,
                                                const short* __restrict__ Wvap,
                                                const float* __restrict__ bva,
                                                float* __restrict__ Vloc) {
    const int t = threadIdx.x, lane = t & 63, w = t >> 6;
    const int r0 = blockIdx.x * 32;
    bf16x8 a[2][4];
#pragma unroll
    for (int rt = 0; rt < 2; ++rt) {
        const float* rowp = hV + (size_t)(r0 + rt * 16 + (lane & 15)) * 128;
#pragma unroll
        for (int kk = 0; kk < 4; ++kk)
            a[rt][kk] = cvt8(rowp + kk * 32 + (lane >> 4) * 8);
    }
    f32x4 acc[2][2] = {};
#pragma unroll
    for (int ct2 = 0; ct2 < 2; ++ct2) {
        const int ct = w * 2 + ct2;
#pragma unroll
        for (int kk = 0; kk < 4; ++kk) {
            bf16x8 b = *(const bf16x8*)(Wvap + ((size_t)(kk * 8 + ct) * 64 + lane) * 8);
            acc[0][ct2] = MFMA(a[0][kk], b, acc[0][ct2]);
            acc[1][ct2] = MFMA(a[1][kk], b, acc[1][ct2]);
        }
    }
#pragma unroll
    for (int ct2 = 0; ct2 < 2; ++ct2) {
        const int c = (w * 2 + ct2) * 16 + (lane & 15);
        if (c < 96) {
            const float bb = bva[c];
#pragma unroll
            for (int rt = 0; rt < 2; ++rt)
#pragma unroll
                for (int r = 0; r < 4; ++r) {
                    int e = rt * 16 + (lane >> 4) * 4 + r;
                    Vloc[(size_t)(r0 + e) * 96 + c] = acc[rt][ct2][r] + bb;
                }
        }
    }
}

__global__ __launch_bounds__(256) void k_w3m(const float* __restrict__ W3,
                                             const float* __restrict__ b3,
                                             const float* __restrict__ Wm,
                                             const float* __restrict__ bm,
                                             float* __restrict__ W3m,
                                             float* __restrict__ bfold) {
    int o = blockIdx.x * blockDim.x + threadIdx.x;
    if (o < 16384) {
        int k = o >> 7, c = o & 127;
        float acc = 0.f;
#pragma unroll 8
        for (int j = 0; j < 128; ++j) acc += W3[k * 128 + j] * Wm[(128 + j) * 128 + c];
        W3m[o] = acc;
    } else if (o < 16512) {
        int c = o - 16384;
        float acc = bm[c];
        for (int j = 0; j < 128; ++j) acc += b3[j] * Wm[(128 + j) * 128 + c];
        bfold[c] = acc;
    }
}

// Fused: geometric features (bf16 H tile in LDS) + V_edge MFMA + L1 MFMA.
__global__ __launch_bounds__(256) void k_feat_l1(
        const float* __restrict__ hE, const float* __restrict__ rot,
        const float* __restrict__ trans, const float* __restrict__ rbf,
        const long long* __restrict__ eidx, const float* __restrict__ Vloc,
        const short* __restrict__ Wvdp, const float* __restrict__ bvd,
        const short* __restrict__ W1p, const float* __restrict__ b1,
        float* __restrict__ Y, float* __restrict__ gsum, float* __restrict__ gsq) {
    __shared__ short Hs[32][HSTR];    // bf16 H tile, cols 0..440 used, 441..447 zero
    __shared__ float rotS[32][9];
    __shared__ float trsS[32][3];
    __shared__ int srcI[32], dstI[32];
    __shared__ float bsum[128], bsq[128];

    const int t = threadIdx.x;
    const int e0 = blockIdx.x * 32;
    const int lane = t & 63, w = t >> 6;

    const int* e32a = (const int*)eidx;
    const bool is64 = (e32a[1] == 0) && (e32a[3] == 0) && (e32a[5] == 0);
    if (t < 32) {
        int s, d;
        if (is64) { s = (int)eidx[e0 + t]; d = (int)eidx[NEDGE + e0 + t]; }
        else      { s = e32a[e0 + t];      d = e32a[NEDGE + e0 + t]; }
        srcI[t] = min(max(s, 0), NATOM - 1);
        dstI[t] = min(max(d, 0), NATOM - 1);
    }
    if (t < 128) { bsum[t] = 0.f; bsq[t] = 0.f; }
    // ---- stage rot/trans/rbf/zero-pad
    for (int o = t; o < 32 * 9; o += 256) {
        int e = o / 9, q = o % 9;
        float v = rot[(size_t)(e0 + e) * 9 + q];
        rotS[e][q] = v; Hs[e][384 + q] = f2bf(v);
    }
    for (int o = t; o < 32 * 3; o += 256) {
        int e = o / 3, q = o % 3;
        trsS[e][q] = trans[(size_t)(e0 + e) * 3 + q];
    }
    for (int o = t; o < 32 * 16; o += 256) {
        int e = o >> 4, q = o & 15;
        Hs[e][393 + q] = f2bf(rbf[(size_t)(e0 + e) * 16 + q]);
    }
    for (int o = t; o < 32 * 7; o += 256) {
        int e = o / 7, q = o % 7;
        Hs[e][441 + q] = 0;
    }
    __syncthreads();

    // ---- Phase B loads (issue early: long-latency global reads)
    bf16x8 afr[2][4];
#pragma unroll
    for (int rt = 0; rt < 2; ++rt) {
        const float* rowp = hE + (size_t)(e0 + rt * 16 + (lane & 15)) * 128;
#pragma unroll
        for (int kk = 0; kk < 4; ++kk)
            afr[rt][kk] = cvt8(rowp + kk * 32 + (lane >> 4) * 8);
    }

    // ---- Phase A1: per-(e,a) Vs/Vd gather, Vs cols, Qt(n=32+a), QRK
    for (int o = t; o < 32 * 32; o += 256) {
        int e = o >> 5, a = o & 31;
        const float* vs = Vloc + (size_t)srcI[e] * 96 + a * 3;
        const float* vd = Vloc + (size_t)dstI[e] * 96 + a * 3;
        float v0 = vs[0], v1 = vs[1], v2 = vs[2];
        float d0 = vd[0], d1 = vd[1], d2 = vd[2];
        float rv0 = rotS[e][0] * v0 + rotS[e][1] * v1 + rotS[e][2] * v2;
        float rv1 = rotS[e][3] * v0 + rotS[e][4] * v1 + rotS[e][5] * v2;
        float rv2 = rotS[e][6] * v0 + rotS[e][7] * v1 + rotS[e][8] * v2;
        Hs[e][96 + 3 * a + 0] = f2bf(v0);
        Hs[e][96 + 3 * a + 1] = f2bf(v1);
        Hs[e][96 + 3 * a + 2] = f2bf(v2);
        Hs[e][288 + 3 * a + 0] = f2bf(rv0 + trsS[e][0]);   // Qt, n = 32+a
        Hs[e][288 + 3 * a + 1] = f2bf(rv1 + trsS[e][1]);
        Hs[e][288 + 3 * a + 2] = f2bf(rv2 + trsS[e][2]);
        Hs[e][409 + a] = f2bf(d0 * rv0 + d1 * rv1 + d2 * rv2);  // QRK
    }

    // ---- Phase B: V_edge = hE @ Wvd + bvd  (cols 0..95)
    {
        f32x4 acc[2][2] = {};
#pragma unroll
        for (int ct2 = 0; ct2 < 2; ++ct2) {
            const int ct = w * 2 + ct2;
#pragma unroll
            for (int kk = 0; kk < 4; ++kk) {
                bf16x8 b = *(const bf16x8*)(Wvdp + ((size_t)(kk * 8 + ct) * 64 + lane) * 8);
                acc[0][ct2] = MFMA(afr[0][kk], b, acc[0][ct2]);
                acc[1][ct2] = MFMA(afr[1][kk], b, acc[1][ct2]);
            }
        }
#pragma unroll
        for (int ct2 = 0; ct2 < 2; ++ct2) {
            const int c = (w * 2 + ct2) * 16 + (lane & 15);
            if (c < 96) {
                const float bb = bvd[c];
#pragma unroll
                for (int rt = 0; rt < 2; ++rt)
#pragma unroll
                    for (int r = 0; r < 4; ++r) {
                        int e = rt * 16 + (lane >> 4) * 4 + r;
                        Hs[e][c] = f2bf(acc[rt][ct2][r] + bb);
                    }
            }
        }
    }
    __syncthreads();

    // ---- Phase B2: Qt for V_edge rows (n = 0..31) from Hs cols 0..95
    for (int o = t; o < 32 * 32; o += 256) {
        int e = o >> 5, n = o & 31;
        float k0 = bf2f(Hs[e][3 * n + 0]);
        float k1 = bf2f(Hs[e][3 * n + 1]);
        float k2 = bf2f(Hs[e][3 * n + 2]);
        Hs[e][192 + 3 * n + 0] = f2bf(rotS[e][0] * k0 + rotS[e][1] * k1 + rotS[e][2] * k2 + trsS[e][0]);
        Hs[e][192 + 3 * n + 1] = f2bf(rotS[e][3] * k0 + rotS[e][4] * k1 + rotS[e][5] * k2 + trsS[e][1]);
        Hs[e][192 + 3 * n + 2] = f2bf(rotS[e][6] * k0 + rotS[e][7] * k1 + rotS[e][8] * k2 + trsS[e][2]);
    }
    __syncthreads();

    // ---- Phase D: Y1 = H @ W1 + b1 (K=448), stats via shfl-reduce
    {
        f32x4 acc[2][2] = {};
#pragma unroll 2
        for (int kk = 0; kk < 14; ++kk) {
            bf16x8 a0 = *(const bf16x8*)&Hs[(lane & 15)][kk * 32 + (lane >> 4) * 8];
            bf16x8 a1 = *(const bf16x8*)&Hs[16 + (lane & 15)][kk * 32 + (lane >> 4) * 8];
            bf16x8 b0 = *(const bf16x8*)(W1p + ((size_t)(kk * 8 + 2 * w) * 64 + lane) * 8);
            bf16x8 b1v = *(const bf16x8*)(W1p + ((size_t)(kk * 8 + 2 * w + 1) * 64 + lane) * 8);
            acc[0][0] = MFMA(a0, b0, acc[0][0]);
            acc[1][0] = MFMA(a1, b0, acc[1][0]);
            acc[0][1] = MFMA(a0, b1v, acc[0][1]);
            acc[1][1] = MFMA(a1, b1v, acc[1][1]);
        }
#pragma unroll
        for (int ct2 = 0; ct2 < 2; ++ct2) {
            const int c = (2 * w + ct2) * 16 + (lane & 15);
            const float bias = b1[c];
            float s = 0.f, sq = 0.f;
#pragma unroll
            for (int rt = 0; rt < 2; ++rt)
#pragma unroll
                for (int r = 0; r < 4; ++r) {
                    int e = rt * 16 + (lane >> 4) * 4 + r;
                    float y = acc[rt][ct2][r] + bias;
                    Y[(size_t)(e0 + e) * 128 + c] = y;
                    s += y; sq += y * y;
                }
            s  += __shfl_xor(s, 16);  s  += __shfl_xor(s, 32);
            sq += __shfl_xor(sq, 16); sq += __shfl_xor(sq, 32);
            if (lane < 16) { atomicAdd(&bsum[c], s); atomicAdd(&bsq[c], sq); }
        }
    }
    __syncthreads();
    if (t < 128) {
        const int slot = blockIdx.x & (NSLOT - 1);
        atomicAdd(&gsum[slot * 128 + t], bsum[t]);
        atomicAdd(&gsq[slot * 128 + t], bsq[t]);
    }
}

__global__ __launch_bounds__(128) void k_stats(const float* __restrict__ gsum,
                                               const float* __restrict__ gsq,
                                               const float* __restrict__ g,
                                               const float* __restrict__ be,
                                               float* __restrict__ a,
                                               float* __restrict__ bb) {
    const int c = threadIdx.x;
    float S = 0.f, Q = 0.f;
    for (int s = 0; s < NSLOT; ++s) { S += gsum[s * 128 + c]; Q += gsq[s * 128 + c]; }
    const float mean = S / (float)NEDGE;
    const float var  = Q / (float)NEDGE - mean * mean;
    const float av   = g[c] * rsqrtf(var + BN_EPS);
    a[c]  = av;
    bb[c] = be[c] - mean * av;
}

// Y2 = relu(bn1(Y1)) @ W2 + b2 (MFMA), in place; accumulate BN2 stats.
__global__ __launch_bounds__(256) void k_l2(float* __restrict__ Y,
                                            const float* __restrict__ a1,
                                            const float* __restrict__ bb1,
                                            const short* __restrict__ W2p,
                                            const float* __restrict__ b2,
                                            float* __restrict__ gsum,
                                            float* __restrict__ gsq) {
    __shared__ short Xs[32][136];
    __shared__ float bsum[128], bsq[128];
    const int t = threadIdx.x, lane = t & 63, w = t >> 6;
    const int e0 = blockIdx.x * 32;
    if (t < 128) { bsum[t] = 0.f; bsq[t] = 0.f; }
    for (int o = t; o < 32 * 128; o += 256) {
        int e = o >> 7, k = o & 127;
        float x = Y[(size_t)(e0 + e) * 128 + k] * a1[k] + bb1[k];
        Xs[e][k] = f2bf(fmaxf(x, 0.f));
    }
    __syncthreads();
    f32x4 acc[2][2] = {};
#pragma unroll
    for (int kk = 0; kk < 4; ++kk) {
        bf16x8 a0 = *(const bf16x8*)&Xs[(lane & 15)][kk * 32 + (lane >> 4) * 8];
        bf16x8 a1f = *(const bf16x8*)&Xs[16 + (lane & 15)][kk * 32 + (lane >> 4) * 8];
        bf16x8 b0 = *(const bf16x8*)(W2p + ((size_t)(kk * 8 + 2 * w) * 64 + lane) * 8);
        bf16x8 b1v = *(const bf16x8*)(W2p + ((size_t)(kk * 8 + 2 * w + 1) * 64 + lane) * 8);
        acc[0][0] = MFMA(a0, b0, acc[0][0]);
        acc[1][0] = MFMA(a1f, b0, acc[1][0]);
        acc[0][1] = MFMA(a0, b1v, acc[0][1]);
        acc[1][1] = MFMA(a1f, b1v, acc[1][1]);
    }
#pragma unroll
    for (int ct2 = 0; ct2 < 2; ++ct2) {
        const int c = (2 * w + ct2) * 16 + (lane & 15);
        const float bias = b2[c];
        float s = 0.f, sq = 0.f;
#pragma unroll
        for (int rt = 0; rt < 2; ++rt)
#pragma unroll
            for (int r = 0; r < 4; ++r) {
                int e = rt * 16 + (lane >> 4) * 4 + r;
                float y = acc[rt][ct2][r] + bias;
                Y[(size_t)(e0 + e) * 128 + c] = y;
                s += y; sq += y * y;
            }
        s  += __shfl_xor(s, 16);  s  += __shfl_xor(s, 32);
        sq += __shfl_xor(sq, 16); sq += __shfl_xor(sq, 32);
        if (lane < 16) { atomicAdd(&bsum[c], s); atomicAdd(&bsq[c], sq); }
    }
    __syncthreads();
    if (t < 128) {
        const int slot = blockIdx.x & (NSLOT - 1);
        atomicAdd(&gsum[slot * 128 + t], bsum[t]);
        atomicAdd(&gsq[slot * 128 + t], bsq[t]);
    }
}

// out = relu(bn2(Y2)) @ W3m + hE @ WmTop + bfold (two fused MFMA GEMMs).
__global__ __launch_bounds__(256) void k_l3(float* __restrict__ Y,
                                            const float* __restrict__ hE,
                                            const float* __restrict__ a2,
                                            const float* __restrict__ bb2,
                                            const short* __restrict__ W3mp,
                                            const short* __restrict__ Wmp,
                                            const float* __restrict__ bfold) {
    __shared__ short Xs[32][136];
    __shared__ short Hes[32][136];
    const int t = threadIdx.x, lane = t & 63, w = t >> 6;
    const int e0 = blockIdx.x * 32;
    for (int o = t; o < 32 * 128; o += 256) {
        int e = o >> 7, k = o & 127;
        float x = Y[(size_t)(e0 + e) * 128 + k] * a2[k] + bb2[k];
        Xs[e][k]  = f2bf(fmaxf(x, 0.f));
        Hes[e][k] = f2bf(hE[(size_t)(e0 + e) * 128 + k]);
    }
    __syncthreads();
    f32x4 acc[2][2] = {};
#pragma unroll
    for (int kk = 0; kk < 4; ++kk) {
        bf16x8 x0 = *(const bf16x8*)&Xs[(lane & 15)][kk * 32 + (lane >> 4) * 8];
        bf16x8 x1 = *(const bf16x8*)&Xs[16 + (lane & 15)][kk * 32 + (lane >> 4) * 8];
        bf16x8 h0 = *(const bf16x8*)&Hes[(lane & 15)][kk * 32 + (lane >> 4) * 8];
        bf16x8 h1 = *(const bf16x8*)&Hes[16 + (lane & 15)][kk * 32 + (lane >> 4) * 8];
        bf16x8 w30 = *(const bf16x8*)(W3mp + ((size_t)(kk * 8 + 2 * w) * 64 + lane) * 8);
        bf16x8 w31 = *(const bf16x8*)(W3mp + ((size_t)(kk * 8 + 2 * w + 1) * 64 + lane) * 8);
        bf16x8 wm0 = *(const bf16x8*)(Wmp + ((size_t)(kk * 8 + 2 * w) * 64 + lane) * 8);
        bf16x8 wm1 = *(const bf16x8*)(Wmp + ((size_t)(kk * 8 + 2 * w + 1) * 64 + lane) * 8);
        acc[0][0] = MFMA(x0, w30, acc[0][0]);
        acc[1][0] = MFMA(x1, w30, acc[1][0]);
        acc[0][1] = MFMA(x0, w31, acc[0][1]);
        acc[1][1] = MFMA(x1, w31, acc[1][1]);
        acc[0][0] = MFMA(h0, wm0, acc[0][0]);
        acc[1][0] = MFMA(h1, wm0, acc[1][0]);
        acc[0][1] = MFMA(h0, wm1, acc[0][1]);
        acc[1][1] = MFMA(h1, wm1, acc[1][1]);
    }
#pragma unroll
    for (int ct2 = 0; ct2 < 2; ++ct2) {
        const int c = (2 * w + ct2) * 16 + (lane & 15);
        const float bias = bfold[c];
#pragma unroll
        for (int rt = 0; rt < 2; ++rt)
#pragma unroll
            for (int r = 0; r < 4; ++r) {
                int e = rt * 16 + (lane >> 4) * 4 + r;
                Y[(size_t)(e0 + e) * 128 + c] = acc[rt][ct2][r] + bias;
            }
    }
}

extern "C" void kernel_launch(void* const* d_in, const int* in_sizes, int n_in,
                              void* d_out, int out_size, void* d_ws, size_t ws_size,
                              hipStream_t stream) {
    const float* hV    = (const float*)d_in[0];
    const float* hE    = (const float*)d_in[1];
    const float* rot   = (const float*)d_in[2];
    const float* trans = (const float*)d_in[3];
    const float* rbf   = (const float*)d_in[4];
    const float* Wva   = (const float*)d_in[6];
    const float* bva   = (const float*)d_in[7];
    const float* Wvd   = (const float*)d_in[8];
    const float* bvd   = (const float*)d_in[9];
    const float* W1    = (const float*)d_in[10];
    const float* b1    = (const float*)d_in[11];
    const float* g1    = (const float*)d_in[12];
    const float* be1   = (const float*)d_in[13];
    const float* W2    = (const float*)d_in[14];
    const float* b2    = (const float*)d_in[15];
    const float* g2    = (const float*)d_in[16];
    const float* be2   = (const float*)d_in[17];
    const float* W3    = (const float*)d_in[18];
    const float* b3    = (const float*)d_in[19];
    const float* Wm    = (const float*)d_in[20];
    const float* bm    = (const float*)d_in[21];
    const long long* eidx = (const long long*)d_in[22];

    float* ws    = (float*)d_ws;
    float* Vloc  = ws;
    float* W3m   = ws + 1920000;
    float* bfold = W3m + 16384;
    float* a1    = bfold + 128;
    float* bb1   = a1 + 128;
    float* a2    = bb1 + 128;
    float* bb2   = a2 + 128;
    float* slots = bb2 + 128;
    float* gsum1 = slots;
    float* gsq1  = slots + NSLOT * 128;
    float* gsum2 = slots + 2 * NSLOT * 128;
    float* gsq2  = slots + 3 * NSLOT * 128;
    short* W1p   = (short*)(slots + 4 * NSLOT * 128);
    short* Wvdp  = W1p + 57344;
    short* W2p   = Wvdp + 16384;
    short* W3mp  = W2p + 16384;
    short* Wmp   = W3mp + 16384;
    short* Wvap  = Wmp + 16384;
    float* Y     = (float*)d_out;

    hipMemsetAsync(slots, 0, (size_t)4 * NSLOT * 128 * sizeof(float), stream);
    k_pack<<<64, 256, 0, stream>>>(Wva, Wvap, 128, 96, 128);
    k_w3m<<<65, 256, 0, stream>>>(W3, b3, Wm, bm, W3m, bfold);
    k_vlocal<<<NATOM / 32, 256, 0, stream>>>(hV, Wvap, bva, Vloc);
    k_pack<<<224, 256, 0, stream>>>(W1, W1p, 441, 128, 448);
    k_pack<<<64, 256, 0, stream>>>(Wvd, Wvdp, 128, 96, 128);
    k_pack<<<64, 256, 0, stream>>>(W2, W2p, 128, 128, 128);
    k_pack<<<64, 256, 0, stream>>>(W3m, W3mp, 128, 128, 128);
    k_pack<<<64, 256, 0, stream>>>(Wm, Wmp, 128, 128, 128);
    k_feat_l1<<<NEDGE / 32, 256, 0, stream>>>(hE, rot, trans, rbf, eidx, Vloc,
                                              Wvdp, bvd, W1p, b1, Y, gsum1, gsq1);
    k_stats<<<1, 128, 0, stream>>>(gsum1, gsq1, g1, be1, a1, bb1);
    k_l2<<<NEDGE / 32, 256, 0, stream>>>(Y, a1, bb1, W2p, b2, gsum2, gsq2);
    k_stats<<<1, 128, 0, stream>>>(gsum2, gsq2, g2, be2, a2, bb2);
    k_l3<<<NEDGE / 32, 256, 0, stream>>>(Y, hE, a2, bb2, W3mp, Wmp, bfold);
}